// Round 2
// baseline (1041.160 us; speedup 1.0000x reference)
//
#include <hip/hip_runtime.h>
#include <hip/hip_bf16.h>
#include <stdint.h>

typedef unsigned short u16;
typedef unsigned int u32;

#define S_LEN 2048
#define HID 2048
#define NH 32
#define NKV 8
#define HD 64

using f32x4 = __attribute__((ext_vector_type(4))) float;
using bfrag = __attribute__((ext_vector_type(8))) short;   // 8 bf16 (4 VGPRs)
using f4v   = __attribute__((ext_vector_type(4))) float;

__device__ __forceinline__ float b2f(u16 u) {
  union { u32 i; float f; } c; c.i = ((u32)u) << 16; return c.f;
}
__device__ __forceinline__ u16 f2b(float f) {
  union { float f; u32 i; } c; c.f = f;
  u32 r = c.i + 0x7fffu + ((c.i >> 16) & 1u);
  return (u16)(r >> 16);
}
// read 8 f32, round to 8 bf16, packed as uint4 (16B) for LDS store
__device__ __forceinline__ uint4 cvt8(const float* __restrict__ p) {
  float4 a = *(const float4*)p;
  float4 b = *(const float4*)(p + 4);
  uint4 r;
  r.x = (u32)f2b(a.x) | ((u32)f2b(a.y) << 16);
  r.y = (u32)f2b(a.z) | ((u32)f2b(a.w) << 16);
  r.z = (u32)f2b(b.x) | ((u32)f2b(b.y) << 16);
  r.w = (u32)f2b(b.z) | ((u32)f2b(b.w) << 16);
  return r;
}

// ------------- NT GEMM (A f32, B f32, bias f32, C bf16): C = A B^T + bias -------------
// 128x128 tile, BK=32, 256 threads (4 waves 2x2), wave does 64x64 via 4x4 MFMA 16x16x32.
__global__ __launch_bounds__(256) void gemm_nt_f2b(
    const float* __restrict__ A, const float* __restrict__ B,
    const float* __restrict__ bias, u16* __restrict__ C,
    int M, int N, int K)
{
  __shared__ short As[128][40];   // +8 pad
  __shared__ short Bs[128][40];

  const int tid  = threadIdx.x;
  const int m0   = blockIdx.y * 128;
  const int n0   = blockIdx.x * 128;
  const int lane = tid & 63;
  const int w    = tid >> 6;
  const int wm   = w >> 1, wn = w & 1;
  const int quad = lane >> 4, l16 = lane & 15;

  f32x4 zero = {0.f, 0.f, 0.f, 0.f};
  f32x4 acc[4][4];
#pragma unroll
  for (int mi = 0; mi < 4; ++mi)
#pragma unroll
    for (int ni = 0; ni < 4; ++ni) acc[mi][ni] = zero;

  for (int k0 = 0; k0 < K; k0 += 32) {
#pragma unroll
    for (int cc = 0; cc < 2; ++cc) {
      int c   = tid + cc * 256;
      int row = c >> 2;
      int kk  = (c & 3) * 8;
      *(uint4*)&As[row][kk] = cvt8(A + (size_t)(m0 + row) * K + k0 + kk);
      *(uint4*)&Bs[row][kk] = cvt8(B + (size_t)(n0 + row) * K + k0 + kk);
    }
    __syncthreads();

    bfrag af[4], bfr[4];
#pragma unroll
    for (int i = 0; i < 4; ++i) {
      af[i]  = *(const bfrag*)&As[wm * 64 + i * 16 + l16][quad * 8];
      bfr[i] = *(const bfrag*)&Bs[wn * 64 + i * 16 + l16][quad * 8];
    }
#pragma unroll
    for (int mi = 0; mi < 4; ++mi)
#pragma unroll
      for (int ni = 0; ni < 4; ++ni)
        acc[mi][ni] = __builtin_amdgcn_mfma_f32_16x16x32_bf16(af[mi], bfr[ni], acc[mi][ni], 0, 0, 0);
    __syncthreads();
  }

  // C/D layout: col=lane&15, row=quad*4+reg (m89-verified)
#pragma unroll
  for (int ni = 0; ni < 4; ++ni) {
    int col = n0 + wn * 64 + ni * 16 + l16;
    float bv = bias ? bias[col] : 0.0f;
#pragma unroll
    for (int mi = 0; mi < 4; ++mi)
#pragma unroll
      for (int i = 0; i < 4; ++i) {
        int row = m0 + wm * 64 + mi * 16 + quad * 4 + i;
        C[(size_t)row * N + col] = f2b(acc[mi][ni][i] + bv);
      }
  }
}

// ------------- NT GEMM (A bf16, B f32, C f32): C = A B^T -------------
__global__ __launch_bounds__(256) void gemm_nt_b2f(
    const u16* __restrict__ A, const float* __restrict__ B,
    float* __restrict__ C, int M, int N, int K)
{
  __shared__ short As[128][40];
  __shared__ short Bs[128][40];

  const int tid  = threadIdx.x;
  const int m0   = blockIdx.y * 128;
  const int n0   = blockIdx.x * 128;
  const int lane = tid & 63;
  const int w    = tid >> 6;
  const int wm   = w >> 1, wn = w & 1;
  const int quad = lane >> 4, l16 = lane & 15;

  f32x4 zero = {0.f, 0.f, 0.f, 0.f};
  f32x4 acc[4][4];
#pragma unroll
  for (int mi = 0; mi < 4; ++mi)
#pragma unroll
    for (int ni = 0; ni < 4; ++ni) acc[mi][ni] = zero;

  for (int k0 = 0; k0 < K; k0 += 32) {
#pragma unroll
    for (int cc = 0; cc < 2; ++cc) {
      int c   = tid + cc * 256;
      int row = c >> 2;
      int kk  = (c & 3) * 8;
      *(uint4*)&As[row][kk] = *(const uint4*)(A + (size_t)(m0 + row) * K + k0 + kk);
      *(uint4*)&Bs[row][kk] = cvt8(B + (size_t)(n0 + row) * K + k0 + kk);
    }
    __syncthreads();

    bfrag af[4], bfr[4];
#pragma unroll
    for (int i = 0; i < 4; ++i) {
      af[i]  = *(const bfrag*)&As[wm * 64 + i * 16 + l16][quad * 8];
      bfr[i] = *(const bfrag*)&Bs[wn * 64 + i * 16 + l16][quad * 8];
    }
#pragma unroll
    for (int mi = 0; mi < 4; ++mi)
#pragma unroll
      for (int ni = 0; ni < 4; ++ni)
        acc[mi][ni] = __builtin_amdgcn_mfma_f32_16x16x32_bf16(af[mi], bfr[ni], acc[mi][ni], 0, 0, 0);
    __syncthreads();
  }

#pragma unroll
  for (int ni = 0; ni < 4; ++ni) {
    int col = n0 + wn * 64 + ni * 16 + l16;
#pragma unroll
    for (int mi = 0; mi < 4; ++mi)
#pragma unroll
      for (int i = 0; i < 4; ++i) {
        int row = m0 + wm * 64 + mi * 16 + quad * 4 + i;
        C[(size_t)row * N + col] = acc[mi][ni][i];
      }
  }
}

// ---------------- RoPE (in-place, bf16 buffer [S, nheads*64]) ----------------
__global__ void rope_k(u16* __restrict__ X, int nheads, int total) {
  int idx = blockIdx.x * blockDim.x + threadIdx.x;
  if (idx >= total) return;
  int d = idx & 31;
  int h = (idx >> 5) % nheads;
  int s = idx / (32 * nheads);
  size_t base = (size_t)s * nheads * 64 + h * 64;
  float x1 = b2f(X[base + d]);
  float x2 = b2f(X[base + d + 32]);
  float inv = exp2f(-(float)d * (13.287712379549449f / 32.0f));  // 10000^(-d/32)
  float ang = (float)s * inv;
  float c = cosf(ang), sn = sinf(ang);
  X[base + d]      = f2b(x1 * c - x2 * sn);
  X[base + d + 32] = f2b(x2 * c + x1 * sn);
}

// ---------------- Flash attention (VALU f32), causal, GQA ----------------
// grid (qtile, head), block 256. Q tile 64x64, KV tiles 64x64, online softmax.
__global__ __launch_bounds__(256) void attn_k(
    const u16* __restrict__ Qg, const u16* __restrict__ Kg,
    const u16* __restrict__ Vg, u16* __restrict__ Og)
{
  __shared__ float Qs[64][68];
  __shared__ float Ks[64][68];
  __shared__ float Ps[64][68];
  __shared__ u16   Vs[64][72];

  const int qb  = blockIdx.x;
  const int h   = blockIdx.y;
  const int kvh = h >> 2;                 // GROUPS=4
  const int tid = threadIdx.x;
  const int tr  = tid >> 4;
  const int tc  = tid & 15;
  const int r0  = tr * 4;
  const int c0  = tc * 4;

  // stage Q tile (bf16 -> f32 LDS)
#pragma unroll
  for (int cc = 0; cc < 2; ++cc) {
    int c = tid + cc * 256;
    int row = c >> 3, ch = (c & 7) * 8;
    uint4 u = *(const uint4*)(Qg + (size_t)(qb * 64 + row) * (NH * HD) + h * 64 + ch);
    f4v a = { b2f((u16)(u.x & 0xffff)), b2f((u16)(u.x >> 16)),
              b2f((u16)(u.y & 0xffff)), b2f((u16)(u.y >> 16)) };
    f4v b = { b2f((u16)(u.z & 0xffff)), b2f((u16)(u.z >> 16)),
              b2f((u16)(u.w & 0xffff)), b2f((u16)(u.w >> 16)) };
    *(f4v*)&Qs[row][ch]     = a;
    *(f4v*)&Qs[row][ch + 4] = b;
  }

  float m_i[4], l_i[4], o[4][4];
#pragma unroll
  for (int i = 0; i < 4; ++i) {
    m_i[i] = -1e30f; l_i[i] = 0.f;
#pragma unroll
    for (int j = 0; j < 4; ++j) o[i][j] = 0.f;
  }

  for (int kb = 0; kb <= qb; ++kb) {
    __syncthreads();
#pragma unroll
    for (int cc = 0; cc < 2; ++cc) {
      int c = tid + cc * 256;
      int row = c >> 3, ch = (c & 7) * 8;
      uint4 uk = *(const uint4*)(Kg + (size_t)(kb * 64 + row) * (NKV * HD) + kvh * 64 + ch);
      f4v a = { b2f((u16)(uk.x & 0xffff)), b2f((u16)(uk.x >> 16)),
                b2f((u16)(uk.y & 0xffff)), b2f((u16)(uk.y >> 16)) };
      f4v b = { b2f((u16)(uk.z & 0xffff)), b2f((u16)(uk.z >> 16)),
                b2f((u16)(uk.w & 0xffff)), b2f((u16)(uk.w >> 16)) };
      *(f4v*)&Ks[row][ch]     = a;
      *(f4v*)&Ks[row][ch + 4] = b;
      uint4 uv = *(const uint4*)(Vg + (size_t)(kb * 64 + row) * (NKV * HD) + kvh * 64 + ch);
      *(uint4*)&Vs[row][ch] = uv;
    }
    __syncthreads();

    // S = QK^T: rows r0..r0+3, cols {tc, tc+16, tc+32, tc+48}
    float s[4][4] = {{0.f,0.f,0.f,0.f},{0.f,0.f,0.f,0.f},{0.f,0.f,0.f,0.f},{0.f,0.f,0.f,0.f}};
#pragma unroll
    for (int d4 = 0; d4 < 16; ++d4) {
      f4v q[4], k[4];
#pragma unroll
      for (int i = 0; i < 4; ++i) q[i] = *(const f4v*)&Qs[r0 + i][d4 * 4];
#pragma unroll
      for (int j = 0; j < 4; ++j) k[j] = *(const f4v*)&Ks[tc + 16 * j][d4 * 4];
#pragma unroll
      for (int i = 0; i < 4; ++i)
#pragma unroll
        for (int j = 0; j < 4; ++j)
          s[i][j] += q[i][0]*k[j][0] + q[i][1]*k[j][1] + q[i][2]*k[j][2] + q[i][3]*k[j][3];
    }

#pragma unroll
    for (int i = 0; i < 4; ++i)
#pragma unroll
      for (int j = 0; j < 4; ++j) {
        float v = s[i][j] * 0.125f;
        v = fminf(50.0f, fmaxf(-50.0f, v));
        int qi = qb * 64 + r0 + i;
        int ki = kb * 64 + tc + 16 * j;
        s[i][j] = (ki <= qi) ? v : -1e30f;
      }

    float pm[4];
#pragma unroll
    for (int i = 0; i < 4; ++i)
      pm[i] = fmaxf(fmaxf(s[i][0], s[i][1]), fmaxf(s[i][2], s[i][3]));
#pragma unroll
    for (int off = 1; off < 16; off <<= 1)
#pragma unroll
      for (int i = 0; i < 4; ++i) pm[i] = fmaxf(pm[i], __shfl_xor(pm[i], off, 64));

    float mn[4], alpha[4], ps[4];
#pragma unroll
    for (int i = 0; i < 4; ++i) {
      mn[i]    = fmaxf(m_i[i], pm[i]);
      alpha[i] = __expf(m_i[i] - mn[i]);
      m_i[i]   = mn[i];
      ps[i]    = 0.f;
    }
#pragma unroll
    for (int i = 0; i < 4; ++i)
#pragma unroll
      for (int j = 0; j < 4; ++j) {
        float p = __expf(s[i][j] - mn[i]);
        s[i][j] = p;
        ps[i] += p;
      }
#pragma unroll
    for (int off = 1; off < 16; off <<= 1)
#pragma unroll
      for (int i = 0; i < 4; ++i) ps[i] += __shfl_xor(ps[i], off, 64);
#pragma unroll
    for (int i = 0; i < 4; ++i) {
      l_i[i] = l_i[i] * alpha[i] + ps[i];
#pragma unroll
      for (int j = 0; j < 4; ++j) o[i][j] *= alpha[i];
    }

#pragma unroll
    for (int i = 0; i < 4; ++i)
#pragma unroll
      for (int j = 0; j < 4; ++j)
        Ps[r0 + i][tc + 16 * j] = s[i][j];
    __syncthreads();

    // O += P * V
#pragma unroll
    for (int j4 = 0; j4 < 16; ++j4) {
      f4v p[4];
#pragma unroll
      for (int i = 0; i < 4; ++i) p[i] = *(const f4v*)&Ps[r0 + i][j4 * 4];
#pragma unroll
      for (int jj = 0; jj < 4; ++jj) {
        ushort4 uv = *(const ushort4*)&Vs[j4 * 4 + jj][c0];
        float v0 = b2f(uv.x), v1 = b2f(uv.y), v2 = b2f(uv.z), v3 = b2f(uv.w);
#pragma unroll
        for (int i = 0; i < 4; ++i) {
          o[i][0] += p[i][jj] * v0;
          o[i][1] += p[i][jj] * v1;
          o[i][2] += p[i][jj] * v2;
          o[i][3] += p[i][jj] * v3;
        }
      }
    }
  }

#pragma unroll
  for (int i = 0; i < 4; ++i) {
    float inv = 1.0f / l_i[i];
#pragma unroll
    for (int j = 0; j < 4; ++j)
      Og[(size_t)(qb * 64 + r0 + i) * (NH * HD) + h * 64 + c0 + j] = f2b(o[i][j] * inv);
  }
}

// ---------------- host launch ----------------
extern "C" void kernel_launch(void* const* d_in, const int* in_sizes, int n_in,
                              void* d_out, int out_size, void* d_ws, size_t ws_size,
                              hipStream_t stream) {
  const float* hid = (const float*)d_in[0];
  // d_in[1] = attention_mask (exactly causal; applied analytically) — unused
  const float* Wq = (const float*)d_in[2];
  const float* bq = (const float*)d_in[3];
  const float* Wk = (const float*)d_in[4];
  const float* bk = (const float*)d_in[5];
  const float* Wv = (const float*)d_in[6];
  const float* bv = (const float*)d_in[7];
  const float* Wo = (const float*)d_in[8];

  u16* Qb = (u16*)d_ws;                       // [2048, 2048] bf16
  u16* Kb = Qb + (size_t)S_LEN * NH * HD;     // [2048, 512]  bf16
  u16* Vb = Kb + (size_t)S_LEN * NKV * HD;    // [2048, 512]  bf16
  u16* Ab = Vb + (size_t)S_LEN * NKV * HD;    // [2048, 2048] bf16
  float* Ob = (float*)d_out;                  // [2048, 2048] f32

  gemm_nt_f2b<<<dim3(16, 16), 256, 0, stream>>>(hid, Wq, bq, Qb, S_LEN, NH * HD, HID);
  gemm_nt_f2b<<<dim3(4, 16), 256, 0, stream>>>(hid, Wk, bk, Kb, S_LEN, NKV * HD, HID);
  gemm_nt_f2b<<<dim3(4, 16), 256, 0, stream>>>(hid, Wv, bv, Vb, S_LEN, NKV * HD, HID);

  int totq = S_LEN * NH * 32;
  int totk = S_LEN * NKV * 32;
  rope_k<<<(totq + 255) / 256, 256, 0, stream>>>(Qb, NH, totq);
  rope_k<<<(totk + 255) / 256, 256, 0, stream>>>(Kb, NKV, totk);

  attn_k<<<dim3(S_LEN / 64, NH), 256, 0, stream>>>(Qb, Kb, Vb, Ab);

  gemm_nt_b2f<<<dim3(16, 16), 256, 0, stream>>>(Ab, Wo, Ob, S_LEN, HID, HID);
}

// Round 3
// 577.062 us; speedup vs baseline: 1.8042x; 1.8042x over previous
//
#include <hip/hip_runtime.h>
#include <hip/hip_bf16.h>
#include <stdint.h>

typedef unsigned short u16;
typedef unsigned int u32;

#define S_LEN 2048
#define HID 2048
#define NH 32
#define NKV 8
#define HD 64

using f32x4 = __attribute__((ext_vector_type(4))) float;
using bfrag = __attribute__((ext_vector_type(8))) short;   // 8 bf16 (4 VGPRs)

__device__ __forceinline__ float b2f(u16 u) {
  union { u32 i; float f; } c; c.i = ((u32)u) << 16; return c.f;
}
__device__ __forceinline__ u16 f2b(float f) {
  union { float f; u32 i; } c; c.f = f;
  u32 r = c.i + 0x7fffu + ((c.i >> 16) & 1u);
  return (u16)(r >> 16);
}
// read 8 f32, round to 8 bf16, packed as uint4 (16B)
__device__ __forceinline__ uint4 cvt8(const float* __restrict__ p) {
  float4 a = *(const float4*)p;
  float4 b = *(const float4*)(p + 4);
  uint4 r;
  r.x = (u32)f2b(a.x) | ((u32)f2b(a.y) << 16);
  r.y = (u32)f2b(a.z) | ((u32)f2b(a.w) << 16);
  r.z = (u32)f2b(b.x) | ((u32)f2b(b.y) << 16);
  r.w = (u32)f2b(b.z) | ((u32)f2b(b.w) << 16);
  return r;
}

// ------------- NT GEMM (A f32, B f32, bias f32, C bf16): C = A B^T + bias -------------
__global__ __launch_bounds__(256) void gemm_nt_f2b(
    const float* __restrict__ A, const float* __restrict__ B,
    const float* __restrict__ bias, u16* __restrict__ C,
    int M, int N, int K)
{
  __shared__ short As[128][40];
  __shared__ short Bs[128][40];

  const int tid  = threadIdx.x;
  const int m0   = blockIdx.y * 128;
  const int n0   = blockIdx.x * 128;
  const int lane = tid & 63;
  const int w    = tid >> 6;
  const int wm   = w >> 1, wn = w & 1;
  const int quad = lane >> 4, l16 = lane & 15;

  f32x4 zero = {0.f, 0.f, 0.f, 0.f};
  f32x4 acc[4][4];
#pragma unroll
  for (int mi = 0; mi < 4; ++mi)
#pragma unroll
    for (int ni = 0; ni < 4; ++ni) acc[mi][ni] = zero;

  for (int k0 = 0; k0 < K; k0 += 32) {
#pragma unroll
    for (int cc = 0; cc < 2; ++cc) {
      int c   = tid + cc * 256;
      int row = c >> 2;
      int kk  = (c & 3) * 8;
      *(uint4*)&As[row][kk] = cvt8(A + (size_t)(m0 + row) * K + k0 + kk);
      *(uint4*)&Bs[row][kk] = cvt8(B + (size_t)(n0 + row) * K + k0 + kk);
    }
    __syncthreads();

    bfrag af[4], bfr[4];
#pragma unroll
    for (int i = 0; i < 4; ++i) {
      af[i]  = *(const bfrag*)&As[wm * 64 + i * 16 + l16][quad * 8];
      bfr[i] = *(const bfrag*)&Bs[wn * 64 + i * 16 + l16][quad * 8];
    }
#pragma unroll
    for (int mi = 0; mi < 4; ++mi)
#pragma unroll
      for (int ni = 0; ni < 4; ++ni)
        acc[mi][ni] = __builtin_amdgcn_mfma_f32_16x16x32_bf16(af[mi], bfr[ni], acc[mi][ni], 0, 0, 0);
    __syncthreads();
  }

#pragma unroll
  for (int ni = 0; ni < 4; ++ni) {
    int col = n0 + wn * 64 + ni * 16 + l16;
    float bv = bias ? bias[col] : 0.0f;
#pragma unroll
    for (int mi = 0; mi < 4; ++mi)
#pragma unroll
      for (int i = 0; i < 4; ++i) {
        int row = m0 + wm * 64 + mi * 16 + quad * 4 + i;
        C[(size_t)row * N + col] = f2b(acc[mi][ni][i] + bv);
      }
  }
}

// ------------- NT GEMM (A bf16, B f32, C f32): C = A B^T -------------
__global__ __launch_bounds__(256) void gemm_nt_b2f(
    const u16* __restrict__ A, const float* __restrict__ B,
    float* __restrict__ C, int M, int N, int K)
{
  __shared__ short As[128][40];
  __shared__ short Bs[128][40];

  const int tid  = threadIdx.x;
  const int m0   = blockIdx.y * 128;
  const int n0   = blockIdx.x * 128;
  const int lane = tid & 63;
  const int w    = tid >> 6;
  const int wm   = w >> 1, wn = w & 1;
  const int quad = lane >> 4, l16 = lane & 15;

  f32x4 zero = {0.f, 0.f, 0.f, 0.f};
  f32x4 acc[4][4];
#pragma unroll
  for (int mi = 0; mi < 4; ++mi)
#pragma unroll
    for (int ni = 0; ni < 4; ++ni) acc[mi][ni] = zero;

  for (int k0 = 0; k0 < K; k0 += 32) {
#pragma unroll
    for (int cc = 0; cc < 2; ++cc) {
      int c   = tid + cc * 256;
      int row = c >> 2;
      int kk  = (c & 3) * 8;
      *(uint4*)&As[row][kk] = *(const uint4*)(A + (size_t)(m0 + row) * K + k0 + kk);
      *(uint4*)&Bs[row][kk] = cvt8(B + (size_t)(n0 + row) * K + k0 + kk);
    }
    __syncthreads();

    bfrag af[4], bfr[4];
#pragma unroll
    for (int i = 0; i < 4; ++i) {
      af[i]  = *(const bfrag*)&As[wm * 64 + i * 16 + l16][quad * 8];
      bfr[i] = *(const bfrag*)&Bs[wn * 64 + i * 16 + l16][quad * 8];
    }
#pragma unroll
    for (int mi = 0; mi < 4; ++mi)
#pragma unroll
      for (int ni = 0; ni < 4; ++ni)
        acc[mi][ni] = __builtin_amdgcn_mfma_f32_16x16x32_bf16(af[mi], bfr[ni], acc[mi][ni], 0, 0, 0);
    __syncthreads();
  }

#pragma unroll
  for (int ni = 0; ni < 4; ++ni) {
    int col = n0 + wn * 64 + ni * 16 + l16;
#pragma unroll
    for (int mi = 0; mi < 4; ++mi)
#pragma unroll
      for (int i = 0; i < 4; ++i) {
        int row = m0 + wm * 64 + mi * 16 + quad * 4 + i;
        C[(size_t)row * N + col] = acc[mi][ni][i];
      }
  }
}

// ---------------- RoPE (in-place, bf16 buffer [S, nheads*64]) ----------------
__global__ void rope_k(u16* __restrict__ X, int nheads, int total) {
  int idx = blockIdx.x * blockDim.x + threadIdx.x;
  if (idx >= total) return;
  int d = idx & 31;
  int h = (idx >> 5) % nheads;
  int s = idx / (32 * nheads);
  size_t base = (size_t)s * nheads * 64 + h * 64;
  float x1 = b2f(X[base + d]);
  float x2 = b2f(X[base + d + 32]);
  float inv = exp2f(-(float)d * (13.287712379549449f / 32.0f));  // 10000^(-d/32)
  float ang = (float)s * inv;
  float c = cosf(ang), sn = sinf(ang);
  X[base + d]      = f2b(x1 * c - x2 * sn);
  X[base + d + 32] = f2b(x2 * c + x1 * sn);
}

// ---------------- MFMA flash attention, causal, GQA ----------------
// grid (qtile 0..31 reversed, head 0..31), block 256 (4 waves).
// Wave w owns q-rows [qb*64 + w*16, +16). Per KV tile (64 keys):
//   QK^T: A = Q-frags (held in regs, loaded once), B = K-frags from LDS.
//   softmax: C-layout rows = quad*4+reg live within one 16-lane quad group
//            -> xor-shuffle reductions, no LDS.
//   P: written bf16 to per-wave LDS strip (C-layout -> A-layout transform,
//      m120 pattern; same-wave only => no barrier needed).
//   PV: A = P-frags, B = Vt-frags (V staged transposed so B reads are b128).
__global__ __launch_bounds__(256) void attn_mfma(
    const u16* __restrict__ Qg, const u16* __restrict__ Kg,
    const u16* __restrict__ Vg, u16* __restrict__ Og)
{
  __shared__ u16 Ks[64][72];      // K tile, row=key, col=d   (stride 144B: 16B-aligned)
  __shared__ u16 Vt[64][72];      // V tile transposed, row=d, col=key
  __shared__ u16 Ps[4][16][72];   // per-wave P strip, row=q(0..15), col=key

  const int qb   = 31 - blockIdx.x;   // big workloads dispatch first
  const int h    = blockIdx.y;
  const int kvh  = h >> 2;            // GROUPS = 4
  const int tid  = threadIdx.x;
  const int lane = tid & 63;
  const int w    = tid >> 6;
  const int quad = lane >> 4, l16 = lane & 15;

  // Q A-fragments, loaded once from global: row = qb*64 + w*16 + l16, d = kf*32 + quad*8
  bfrag qf[2];
  {
    const u16* qrow = Qg + (size_t)(qb * 64 + w * 16 + l16) * (NH * HD) + h * 64;
    qf[0] = *(const bfrag*)(qrow + quad * 8);
    qf[1] = *(const bfrag*)(qrow + 32 + quad * 8);
  }

  f32x4 zero = {0.f, 0.f, 0.f, 0.f};
  f32x4 o_acc[4];
  float m_i[4], l_i[4];
#pragma unroll
  for (int i = 0; i < 4; ++i) { o_acc[i] = zero; m_i[i] = -1e30f; l_i[i] = 0.f; }

  for (int kb = 0; kb <= qb; ++kb) {
    __syncthreads();   // prior-iter Ks/Vt reads done before restaging
    // stage K (as-is) and V (transposed): 64 rows x 64 cols bf16 each
#pragma unroll
    for (int cc = 0; cc < 2; ++cc) {
      int c   = tid + cc * 256;     // 0..511
      int row = c >> 3;             // key index 0..63
      int ch  = (c & 7) * 8;        // d offset 0,8,..,56
      size_t goff = (size_t)(kb * 64 + row) * (NKV * HD) + kvh * 64 + ch;
      *(uint4*)&Ks[row][ch] = *(const uint4*)(Kg + goff);
      ushort4 v0 = *(const ushort4*)(Vg + goff);
      ushort4 v1 = *(const ushort4*)(Vg + goff + 4);
      Vt[ch + 0][row] = v0.x; Vt[ch + 1][row] = v0.y;
      Vt[ch + 2][row] = v0.z; Vt[ch + 3][row] = v0.w;
      Vt[ch + 4][row] = v1.x; Vt[ch + 5][row] = v1.y;
      Vt[ch + 6][row] = v1.z; Vt[ch + 7][row] = v1.w;
    }
    __syncthreads();

    // ---- S = Q K^T (16 q-rows x 64 keys per wave) ----
    f32x4 s_acc[4];
#pragma unroll
    for (int nb = 0; nb < 4; ++nb) {
      s_acc[nb] = zero;
      bfrag k0 = *(const bfrag*)&Ks[nb * 16 + l16][quad * 8];
      bfrag k1 = *(const bfrag*)&Ks[nb * 16 + l16][32 + quad * 8];
      s_acc[nb] = __builtin_amdgcn_mfma_f32_16x16x32_bf16(qf[0], k0, s_acc[nb], 0, 0, 0);
      s_acc[nb] = __builtin_amdgcn_mfma_f32_16x16x32_bf16(qf[1], k1, s_acc[nb], 0, 0, 0);
    }

    // ---- softmax (rows = quad*4 + i, cols = kb*64 + nb*16 + l16) ----
    float sv[4][4];
#pragma unroll
    for (int nb = 0; nb < 4; ++nb)
#pragma unroll
      for (int i = 0; i < 4; ++i) {
        float v = s_acc[nb][i] * 0.125f;
        sv[nb][i] = fminf(50.0f, fmaxf(-50.0f, v));
      }
    if (kb == qb) {   // wave-uniform branch; mask only on the diagonal tile
#pragma unroll
      for (int nb = 0; nb < 4; ++nb)
#pragma unroll
        for (int i = 0; i < 4; ++i)
          if (nb * 16 + l16 > w * 16 + quad * 4 + i) sv[nb][i] = -1e30f;
    }

    float pm[4];
#pragma unroll
    for (int i = 0; i < 4; ++i)
      pm[i] = fmaxf(fmaxf(sv[0][i], sv[1][i]), fmaxf(sv[2][i], sv[3][i]));
#pragma unroll
    for (int off = 1; off < 16; off <<= 1)
#pragma unroll
      for (int i = 0; i < 4; ++i) pm[i] = fmaxf(pm[i], __shfl_xor(pm[i], off, 64));

    float mn[4], alpha[4], ps[4];
#pragma unroll
    for (int i = 0; i < 4; ++i) {
      mn[i]    = fmaxf(m_i[i], pm[i]);
      alpha[i] = __expf(m_i[i] - mn[i]);
      m_i[i]   = mn[i];
      ps[i]    = 0.f;
    }
#pragma unroll
    for (int nb = 0; nb < 4; ++nb)
#pragma unroll
      for (int i = 0; i < 4; ++i) {
        float p = __expf(sv[nb][i] - mn[i]);
        sv[nb][i] = p;
        ps[i] += p;
      }
#pragma unroll
    for (int off = 1; off < 16; off <<= 1)
#pragma unroll
      for (int i = 0; i < 4; ++i) ps[i] += __shfl_xor(ps[i], off, 64);
#pragma unroll
    for (int i = 0; i < 4; ++i) {
      l_i[i] = l_i[i] * alpha[i] + ps[i];
#pragma unroll
      for (int nb = 0; nb < 4; ++nb) o_acc[nb][i] *= alpha[i];
    }

    // ---- P: C-layout -> A-layout via per-wave LDS strip ----
#pragma unroll
    for (int nb = 0; nb < 4; ++nb)
#pragma unroll
      for (int i = 0; i < 4; ++i)
        Ps[w][quad * 4 + i][nb * 16 + l16] = f2b(sv[nb][i]);
    // same-wave RAW: compiler inserts lgkmcnt wait (LDS may-alias)

    bfrag pf0 = *(const bfrag*)&Ps[w][l16][quad * 8];
    bfrag pf1 = *(const bfrag*)&Ps[w][l16][32 + quad * 8];
#pragma unroll
    for (int nb = 0; nb < 4; ++nb) {
      bfrag v0 = *(const bfrag*)&Vt[nb * 16 + l16][quad * 8];
      bfrag v1 = *(const bfrag*)&Vt[nb * 16 + l16][32 + quad * 8];
      o_acc[nb] = __builtin_amdgcn_mfma_f32_16x16x32_bf16(pf0, v0, o_acc[nb], 0, 0, 0);
      o_acc[nb] = __builtin_amdgcn_mfma_f32_16x16x32_bf16(pf1, v1, o_acc[nb], 0, 0, 0);
    }
  }

  // epilogue: row = qb*64 + w*16 + quad*4 + i, col d = nb*16 + l16
#pragma unroll
  for (int i = 0; i < 4; ++i) {
    float inv = 1.0f / l_i[i];
    size_t rbase = (size_t)(qb * 64 + w * 16 + quad * 4 + i) * (NH * HD) + h * 64;
#pragma unroll
    for (int nb = 0; nb < 4; ++nb)
      Og[rbase + nb * 16 + l16] = f2b(o_acc[nb][i] * inv);
  }
}

// ---------------- host launch ----------------
extern "C" void kernel_launch(void* const* d_in, const int* in_sizes, int n_in,
                              void* d_out, int out_size, void* d_ws, size_t ws_size,
                              hipStream_t stream) {
  const float* hid = (const float*)d_in[0];
  // d_in[1] = attention_mask (exactly causal; applied analytically) — unused
  const float* Wq = (const float*)d_in[2];
  const float* bq = (const float*)d_in[3];
  const float* Wk = (const float*)d_in[4];
  const float* bk = (const float*)d_in[5];
  const float* Wv = (const float*)d_in[6];
  const float* bv = (const float*)d_in[7];
  const float* Wo = (const float*)d_in[8];

  u16* Qb = (u16*)d_ws;                       // [2048, 2048] bf16
  u16* Kb = Qb + (size_t)S_LEN * NH * HD;     // [2048, 512]  bf16
  u16* Vb = Kb + (size_t)S_LEN * NKV * HD;    // [2048, 512]  bf16
  u16* Ab = Vb + (size_t)S_LEN * NKV * HD;    // [2048, 2048] bf16
  float* Ob = (float*)d_out;                  // [2048, 2048] f32

  gemm_nt_f2b<<<dim3(16, 16), 256, 0, stream>>>(hid, Wq, bq, Qb, S_LEN, NH * HD, HID);
  gemm_nt_f2b<<<dim3(4, 16), 256, 0, stream>>>(hid, Wk, bk, Kb, S_LEN, NKV * HD, HID);
  gemm_nt_f2b<<<dim3(4, 16), 256, 0, stream>>>(hid, Wv, bv, Vb, S_LEN, NKV * HD, HID);

  int totq = S_LEN * NH * 32;
  int totk = S_LEN * NKV * 32;
  rope_k<<<(totq + 255) / 256, 256, 0, stream>>>(Qb, NH, totq);
  rope_k<<<(totk + 255) / 256, 256, 0, stream>>>(Kb, NKV, totk);

  attn_mfma<<<dim3(S_LEN / 64, NH), 256, 0, stream>>>(Qb, Kb, Vb, Ab);

  gemm_nt_b2f<<<dim3(16, 16), 256, 0, stream>>>(Ab, Wo, Ob, S_LEN, HID, HID);
}

// Round 4
// 541.577 us; speedup vs baseline: 1.9225x; 1.0655x over previous
//
#include <hip/hip_runtime.h>
#include <hip/hip_bf16.h>
#include <stdint.h>

typedef unsigned short u16;
typedef unsigned int u32;

#define S_LEN 2048
#define HID 2048
#define NH 32
#define NKV 8
#define HD 64

using f32x4 = __attribute__((ext_vector_type(4))) float;
using bfrag = __attribute__((ext_vector_type(8))) short;   // 8 bf16 (4 VGPRs)

__device__ __forceinline__ float b2f(u16 u) {
  union { u32 i; float f; } c; c.i = ((u32)u) << 16; return c.f;
}
__device__ __forceinline__ u16 f2b(float f) {
  union { float f; u32 i; } c; c.f = f;
  u32 r = c.i + 0x7fffu + ((c.i >> 16) & 1u);
  return (u16)(r >> 16);
}
__device__ __forceinline__ uint4 cvt8(const float* __restrict__ p) {
  float4 a = *(const float4*)p;
  float4 b = *(const float4*)(p + 4);
  uint4 r;
  r.x = (u32)f2b(a.x) | ((u32)f2b(a.y) << 16);
  r.y = (u32)f2b(a.z) | ((u32)f2b(a.w) << 16);
  r.z = (u32)f2b(b.x) | ((u32)f2b(b.y) << 16);
  r.w = (u32)f2b(b.z) | ((u32)f2b(b.w) << 16);
  return r;
}

// async global->LDS, 16B per lane; LDS dest = wave-uniform base + lane*16 (m97/m104)
__device__ __forceinline__ void gl2lds16(const u16* g, u16* l) {
  __builtin_amdgcn_global_load_lds(
      (const __attribute__((address_space(1))) void*)g,
      (__attribute__((address_space(3))) void*)l, 16, 0, 0);
}

// ---------------- f32 -> bf16 convert (8 elems/thread) ----------------
__global__ void conv_f2b(const float* __restrict__ in, u16* __restrict__ out, int n8) {
  int i = blockIdx.x * 256 + threadIdx.x;
  if (i >= n8) return;
  *(uint4*)(out + (size_t)i * 8) = cvt8(in + (size_t)i * 8);
}

// ---------------- fused QKV GEMM (m97-style) + bias + RoPE + V-transpose ----------------
// C[M=2048, N=3072] = hidb * Wb^T ; Wb rows: [0,2048)=Wq, [2048,2560)=Wk, [2560,3072)=Wv.
// cols <2048 -> RoPE -> Qb[s][2048]; cols 2048..2559 -> RoPE -> Kb[s][512];
// cols 2560..3071 -> Vt[d][s] (transposed).
__global__ __launch_bounds__(256) void gemm_qkv(
    const u16* __restrict__ A, const u16* __restrict__ B,
    const float* __restrict__ bq, const float* __restrict__ bk, const float* __restrict__ bv,
    u16* __restrict__ Qb, u16* __restrict__ Kb, u16* __restrict__ Vt)
{
  __shared__ u16 As[128 * 32];   // unpadded: required by global_load_lds lane mapping
  __shared__ u16 Bs[128 * 32];

  const int tid  = threadIdx.x;
  const int m0   = blockIdx.y * 128;
  const int n0   = blockIdx.x * 128;
  const int lane = tid & 63;
  const int w    = tid >> 6;
  const int wm   = w >> 1, wn = w & 1;
  const int quad = lane >> 4, l16 = lane & 15;

  // staging map: slot = w*2+j; row = slot*16 + lane/4; col = (lane&3)*8
  const int srow0 = (w * 2) * 16 + (lane >> 2);
  const int srow1 = (w * 2 + 1) * 16 + (lane >> 2);
  const int scol  = (lane & 3) * 8;

  f32x4 zero = {0.f, 0.f, 0.f, 0.f};
  f32x4 acc[4][4];
#pragma unroll
  for (int mi = 0; mi < 4; ++mi)
#pragma unroll
    for (int ni = 0; ni < 4; ++ni) acc[mi][ni] = zero;

  for (int k0 = 0; k0 < HID; k0 += 32) {
    gl2lds16(A + (size_t)(m0 + srow0) * HID + k0 + scol, As + (w * 2) * 512);
    gl2lds16(A + (size_t)(m0 + srow1) * HID + k0 + scol, As + (w * 2 + 1) * 512);
    gl2lds16(B + (size_t)(n0 + srow0) * HID + k0 + scol, Bs + (w * 2) * 512);
    gl2lds16(B + (size_t)(n0 + srow1) * HID + k0 + scol, Bs + (w * 2 + 1) * 512);
    __syncthreads();

    bfrag af[4], bf[4];
#pragma unroll
    for (int i = 0; i < 4; ++i) {
      af[i] = *(const bfrag*)&As[(wm * 64 + i * 16 + l16) * 32 + quad * 8];
      bf[i] = *(const bfrag*)&Bs[(wn * 64 + i * 16 + l16) * 32 + quad * 8];
    }
#pragma unroll
    for (int mi = 0; mi < 4; ++mi)
#pragma unroll
      for (int ni = 0; ni < 4; ++ni)
        acc[mi][ni] = __builtin_amdgcn_mfma_f32_16x16x32_bf16(af[mi], bf[ni], acc[mi][ni], 0, 0, 0);
    __syncthreads();
  }

  // ---- epilogue (C/D layout: col=l16-based, row=quad*4+reg) ----
  if (n0 < 2048) {          // Q + RoPE
#pragma unroll
    for (int mi = 0; mi < 4; ++mi)
#pragma unroll
      for (int i = 0; i < 4; ++i) {
        int srow = m0 + wm * 64 + mi * 16 + quad * 4 + i;
#pragma unroll
        for (int n01 = 0; n01 < 2; ++n01) {
          int c1 = n0 + wn * 64 + n01 * 16 + l16;
          int d  = n01 * 16 + l16;                  // 0..31
          float x1 = acc[mi][n01][i]     + bq[c1];
          float x2 = acc[mi][n01 + 2][i] + bq[c1 + 32];
          float inv = exp2f(-(float)d * 0.41524101186092034f); // log2(1e4)/32
          float ang = (float)srow * inv;
          float cs = cosf(ang), sn = sinf(ang);
          Qb[(size_t)srow * 2048 + c1]      = f2b(x1 * cs - x2 * sn);
          Qb[(size_t)srow * 2048 + c1 + 32] = f2b(x2 * cs + x1 * sn);
        }
      }
  } else if (n0 < 2560) {   // K + RoPE
#pragma unroll
    for (int mi = 0; mi < 4; ++mi)
#pragma unroll
      for (int i = 0; i < 4; ++i) {
        int srow = m0 + wm * 64 + mi * 16 + quad * 4 + i;
#pragma unroll
        for (int n01 = 0; n01 < 2; ++n01) {
          int cg = (n0 - 2048) + wn * 64 + n01 * 16 + l16;   // 0..511
          int d  = n01 * 16 + l16;
          float x1 = acc[mi][n01][i]     + bk[cg];
          float x2 = acc[mi][n01 + 2][i] + bk[cg + 32];
          float inv = exp2f(-(float)d * 0.41524101186092034f);
          float ang = (float)srow * inv;
          float cs = cosf(ang), sn = sinf(ang);
          Kb[(size_t)srow * 512 + cg]      = f2b(x1 * cs - x2 * sn);
          Kb[(size_t)srow * 512 + cg + 32] = f2b(x2 * cs + x1 * sn);
        }
      }
  } else {                  // V, transposed store Vt[col][s]
#pragma unroll
    for (int ni = 0; ni < 4; ++ni) {
      int cg = (n0 - 2560) + wn * 64 + ni * 16 + l16;        // 0..511
      float bvv = bv[cg];
#pragma unroll
      for (int mi = 0; mi < 4; ++mi)
#pragma unroll
        for (int i = 0; i < 4; ++i) {
          int srow = m0 + wm * 64 + mi * 16 + quad * 4 + i;
          Vt[(size_t)cg * 2048 + srow] = f2b(acc[mi][ni][i] + bvv);
        }
    }
  }
}

// ---------------- O-proj GEMM (m97-style): C f32 = Ab(bf16) * Wob(bf16)^T ----------------
__global__ __launch_bounds__(256) void gemm_o(
    const u16* __restrict__ A, const u16* __restrict__ B, float* __restrict__ C)
{
  __shared__ u16 As[128 * 32];
  __shared__ u16 Bs[128 * 32];

  const int tid  = threadIdx.x;
  const int m0   = blockIdx.y * 128;
  const int n0   = blockIdx.x * 128;
  const int lane = tid & 63;
  const int w    = tid >> 6;
  const int wm   = w >> 1, wn = w & 1;
  const int quad = lane >> 4, l16 = lane & 15;

  const int srow0 = (w * 2) * 16 + (lane >> 2);
  const int srow1 = (w * 2 + 1) * 16 + (lane >> 2);
  const int scol  = (lane & 3) * 8;

  f32x4 zero = {0.f, 0.f, 0.f, 0.f};
  f32x4 acc[4][4];
#pragma unroll
  for (int mi = 0; mi < 4; ++mi)
#pragma unroll
    for (int ni = 0; ni < 4; ++ni) acc[mi][ni] = zero;

  for (int k0 = 0; k0 < HID; k0 += 32) {
    gl2lds16(A + (size_t)(m0 + srow0) * HID + k0 + scol, As + (w * 2) * 512);
    gl2lds16(A + (size_t)(m0 + srow1) * HID + k0 + scol, As + (w * 2 + 1) * 512);
    gl2lds16(B + (size_t)(n0 + srow0) * HID + k0 + scol, Bs + (w * 2) * 512);
    gl2lds16(B + (size_t)(n0 + srow1) * HID + k0 + scol, Bs + (w * 2 + 1) * 512);
    __syncthreads();

    bfrag af[4], bf[4];
#pragma unroll
    for (int i = 0; i < 4; ++i) {
      af[i] = *(const bfrag*)&As[(wm * 64 + i * 16 + l16) * 32 + quad * 8];
      bf[i] = *(const bfrag*)&Bs[(wn * 64 + i * 16 + l16) * 32 + quad * 8];
    }
#pragma unroll
    for (int mi = 0; mi < 4; ++mi)
#pragma unroll
      for (int ni = 0; ni < 4; ++ni)
        acc[mi][ni] = __builtin_amdgcn_mfma_f32_16x16x32_bf16(af[mi], bf[ni], acc[mi][ni], 0, 0, 0);
    __syncthreads();
  }

#pragma unroll
  for (int ni = 0; ni < 4; ++ni) {
    int col = n0 + wn * 64 + ni * 16 + l16;
#pragma unroll
    for (int mi = 0; mi < 4; ++mi)
#pragma unroll
      for (int i = 0; i < 4; ++i) {
        int row = m0 + wm * 64 + mi * 16 + quad * 4 + i;
        C[(size_t)row * 2048 + col] = acc[mi][ni][i];
      }
  }
}

// ---------------- barrier-free MFMA flash attention ----------------
// grid (h=32, qbb-rev=16), block 256. Wave w owns rows {qbb*128 + g*64 + w*16 .. +16} for g=0,1.
// K/V fragments loaded directly from global (L1/L2-served); only LDS = per-wave P strips.
// Fixed-max softmax (scores clipped to +-50 => exp(s) cannot over/underflow in f32);
// l reduced across 16 lanes once, after the KV loop.
__global__ __launch_bounds__(256) void attn_flash2(
    const u16* __restrict__ Qb, const u16* __restrict__ Kb,
    const u16* __restrict__ Vt, u16* __restrict__ Ab)
{
  __shared__ u16 Ps[4][2][16][72];   // [wave][g][qrow 0..15][key 0..63 (+pad)]

  const int h    = blockIdx.x;
  const int qbb  = 15 - (int)blockIdx.y;   // big workloads first
  const int kvh  = h >> 2;                 // GROUPS = 4
  const int tid  = threadIdx.x;
  const int lane = tid & 63;
  const int w    = tid >> 6;
  const int quad = lane >> 4, l16 = lane & 15;

  // Q A-frags (row = ..., k = quad*8+j), loaded once
  bfrag qf[2][2];
#pragma unroll
  for (int g = 0; g < 2; ++g) {
    const u16* qp = Qb + (size_t)(qbb * 128 + g * 64 + w * 16 + l16) * 2048 + h * 64 + quad * 8;
    qf[g][0] = *(const bfrag*)qp;
    qf[g][1] = *(const bfrag*)(qp + 32);
  }

  f32x4 zero = {0.f, 0.f, 0.f, 0.f};
  f32x4 o_acc[2][4];
  float lpart[2][4];
#pragma unroll
  for (int g = 0; g < 2; ++g)
#pragma unroll
    for (int nb = 0; nb < 4; ++nb) { o_acc[g][nb] = zero; lpart[g][nb] = 0.f; }

  const int kbmax = 2 * qbb + 1;
  for (int kb = 0; kb <= kbmax; ++kb) {
    // K B-frags from global: lane l16 = key, quad*8+j = d
    bfrag kf0[4], kf1[4];
#pragma unroll
    for (int nb = 0; nb < 4; ++nb) {
      const u16* kp = Kb + (size_t)(kb * 64 + nb * 16 + l16) * 512 + kvh * 64 + quad * 8;
      kf0[nb] = *(const bfrag*)kp;
      kf1[nb] = *(const bfrag*)(kp + 32);
    }

#pragma unroll
    for (int g = 0; g < 2; ++g) {
      int t = 2 * qbb + g;
      if (kb > t) continue;            // wave-uniform (only g=0 skips, at kb==kbmax)
      f32x4 s_acc[4];
#pragma unroll
      for (int nb = 0; nb < 4; ++nb) {
        s_acc[nb] = __builtin_amdgcn_mfma_f32_16x16x32_bf16(qf[g][0], kf0[nb], zero, 0, 0, 0);
        s_acc[nb] = __builtin_amdgcn_mfma_f32_16x16x32_bf16(qf[g][1], kf1[nb], s_acc[nb], 0, 0, 0);
      }
      bool diag = (kb == t);
#pragma unroll
      for (int nb = 0; nb < 4; ++nb)
#pragma unroll
        for (int i = 0; i < 4; ++i) {
          float v = s_acc[nb][i] * 0.125f;
          v = fminf(50.0f, fmaxf(-50.0f, v));
          bool msk = diag && (nb * 16 + l16 > w * 16 + quad * 4 + i);
          float p = msk ? 0.0f : __expf(v);
          lpart[g][i] += p;
          Ps[w][g][quad * 4 + i][nb * 16 + l16] = f2b(p);
        }
    }

    // V B-frags from pre-transposed Vt: lane l16 = d, quad*8+j = key
    bfrag vf0[4], vf1[4];
#pragma unroll
    for (int nb = 0; nb < 4; ++nb) {
      const u16* vp = Vt + (size_t)(kvh * 64 + nb * 16 + l16) * 2048 + kb * 64 + quad * 8;
      vf0[nb] = *(const bfrag*)vp;
      vf1[nb] = *(const bfrag*)(vp + 32);
    }
#pragma unroll
    for (int g = 0; g < 2; ++g) {
      if (kb > 2 * qbb + g) continue;
      bfrag pf0 = *(const bfrag*)&Ps[w][g][l16][quad * 8];
      bfrag pf1 = *(const bfrag*)&Ps[w][g][l16][32 + quad * 8];
#pragma unroll
      for (int nb = 0; nb < 4; ++nb) {
        o_acc[g][nb] = __builtin_amdgcn_mfma_f32_16x16x32_bf16(pf0, vf0[nb], o_acc[g][nb], 0, 0, 0);
        o_acc[g][nb] = __builtin_amdgcn_mfma_f32_16x16x32_bf16(pf1, vf1[nb], o_acc[g][nb], 0, 0, 0);
      }
    }
  }

  // final 16-lane row-sum reduce of l (rows live within a quad's 16-lane group)
#pragma unroll
  for (int off = 1; off < 16; off <<= 1)
#pragma unroll
    for (int g = 0; g < 2; ++g)
#pragma unroll
      for (int i = 0; i < 4; ++i)
        lpart[g][i] += __shfl_xor(lpart[g][i], off, 64);

#pragma unroll
  for (int g = 0; g < 2; ++g)
#pragma unroll
    for (int i = 0; i < 4; ++i) {
      float inv = 1.0f / lpart[g][i];
      size_t rbase = (size_t)(qbb * 128 + g * 64 + w * 16 + quad * 4 + i) * 2048 + h * 64;
#pragma unroll
      for (int nb = 0; nb < 4; ++nb)
        Ab[rbase + nb * 16 + l16] = f2b(o_acc[g][nb][i] * inv);
    }
}

// ---------------- host launch ----------------
extern "C" void kernel_launch(void* const* d_in, const int* in_sizes, int n_in,
                              void* d_out, int out_size, void* d_ws, size_t ws_size,
                              hipStream_t stream) {
  const float* hid = (const float*)d_in[0];
  // d_in[1] = attention_mask (exactly causal; applied analytically) — unused
  const float* Wq = (const float*)d_in[2];
  const float* bq = (const float*)d_in[3];
  const float* Wk = (const float*)d_in[4];
  const float* bk = (const float*)d_in[5];
  const float* Wv = (const float*)d_in[6];
  const float* bv = (const float*)d_in[7];
  const float* Wo = (const float*)d_in[8];

  // ws layout (u16 elems), 32 MB total with reuse:
  u16* hidb  = (u16*)d_ws;                 // [2048][2048]  8MB  -> reused as Ab
  u16* Wqkvb = hidb + 4194304;             // [3072][2048] 12MB  -> first 8MB reused as Wob
  u16* Qb    = Wqkvb + 6291456;            // [2048][2048]  8MB
  u16* Kb    = Qb + 4194304;               // [2048][512]   2MB
  u16* Vt    = Kb + 1048576;               // [512][2048]   2MB
  u16* Ab    = hidb;                       // reuse (hidb dead after gemm_qkv)
  u16* Wob   = Wqkvb;                      // reuse (Wqkv dead after gemm_qkv)
  float* Ob  = (float*)d_out;

  // f32 -> bf16 converts
  conv_f2b<<<2048, 256, 0, stream>>>(hid, hidb, 524288);
  conv_f2b<<<2048, 256, 0, stream>>>(Wq, Wqkvb, 524288);
  conv_f2b<<<512, 256, 0, stream>>>(Wk, Wqkvb + 4194304, 131072);
  conv_f2b<<<512, 256, 0, stream>>>(Wv, Wqkvb + 5242880, 131072);

  // fused QKV projection + bias + RoPE + V-transpose
  gemm_qkv<<<dim3(24, 16), 256, 0, stream>>>(hidb, Wqkvb, bq, bk, bv, Qb, Kb, Vt);

  // convert Wo into the (now dead) Wqkv region
  conv_f2b<<<2048, 256, 0, stream>>>(Wo, Wob, 524288);

  // attention
  attn_flash2<<<dim3(32, 16), 256, 0, stream>>>(Qb, Kb, Vt, Ab);

  // output projection (f32 out)
  gemm_o<<<dim3(16, 16), 256, 0, stream>>>(Ab, Wob, Ob);
}